// Round 3
// baseline (489.953 us; speedup 1.0000x reference)
//
#include <hip/hip_runtime.h>
#include <math.h>

#define NB 32
#define NT 512
#define NC 4233
#define NU 64
#define LABT 129            // 2*NU+1
#define PADV (-3.4028234663852886e38f)   // float32 min (matches jnp.finfo(f32).min)
#define SCANBLK 192

// ---------------------------------------------------------------------------
// Kernel 0: build ext_idx[b][j], cond[b][j], yl[b]
// ---------------------------------------------------------------------------
__global__ void ctc_prep_kernel(const int* __restrict__ label,   // [U][B]
                                const int* __restrict__ blank_ptr,
                                int* __restrict__ ext_idx,        // [B][LABT]
                                int* __restrict__ cond,           // [B][LABT]
                                int* __restrict__ yl)             // [B]
{
    const int b = blockIdx.x;
    const int j = threadIdx.x;
    const int blank = blank_ptr[0];

    // yl = 2 * count(label != blank) + 1, via wave-0 ballot (U == 64 == wave size)
    if (j < 64) {
        int raw = label[j * NB + b];
        unsigned long long m = __ballot(raw != blank);
        if (j == 0) yl[b] = 2 * (int)__popcll(m) + 1;
    }

    if (j < LABT) {
        int extv;
        if ((j & 1) == 0) {
            extv = blank;
        } else {
            int raw = label[((j - 1) >> 1) * NB + b];
            extv = (raw == blank) ? -1 : raw;
        }
        int sh2;  // ext shifted right by 2, pad -1
        if (j < 2) {
            sh2 = -1;
        } else if (((j - 2) & 1) == 0) {
            sh2 = blank;
        } else {
            int raw2 = label[((j - 3) >> 1) * NB + b];
            sh2 = (raw2 == blank) ? -1 : raw2;
        }
        int c = (extv == blank) || (extv == sh2);
        int idx = extv % NC;            // python floor-mod for -1 -> NC-1
        if (idx < 0) idx += NC;
        ext_idx[b * LABT + j] = idx;
        cond[b * LABT + j]    = c;
    }
}

// ---------------------------------------------------------------------------
// Kernel 1: forward DP scan + loss + Viterbi backtrack.  One block per batch.
// ---------------------------------------------------------------------------
__global__ __launch_bounds__(SCANBLK)
void ctc_scan_kernel(const float* __restrict__ logit,   // [B][T][C] log-probs
                     const int*   __restrict__ ext_idx, // [B][LABT]
                     const int*   __restrict__ cond,    // [B][LABT]
                     const int*   __restrict__ yl,      // [B]
                     int*   __restrict__ wout,          // [B][T] viterbi state
                     float* __restrict__ loss_out)      // [B] float loss
{
    __shared__ float dbuf[2][SCANBLK + 8];
    __shared__ unsigned long long bpm[NT][3][2];  // 2-bit backptr, ballot-packed
    __shared__ int wl[NT];

    const int b = blockIdx.x;
    const int j = threadIdx.x;
    const bool act = (j < LABT);

    const int col = act ? ext_idx[b * LABT + j] : 0;  // inactive lanes read blank col
    const int cnd = act ? cond[b * LABT + j] : 1;

    const float* lb = logit + (size_t)b * NT * NC;

    float* pa = dbuf[0];
    float* pb = dbuf[1];

    // t = 0 init: dp0[0] = emit[0][0], dp0[1] = emit[0][1], else PAD
    float e0 = lb[col];
    pa[j] = (j <= 1) ? e0 : PADV;

    // prefetch ring for t = 1..4
    float r0 = lb[(size_t)1 * NC + col];
    float r1 = lb[(size_t)2 * NC + col];
    float r2 = lb[(size_t)3 * NC + col];
    float r3 = lb[(size_t)4 * NC + col];
    __syncthreads();

#define STEP(tcur, rr, tload)                                                  \
    do {                                                                       \
        float a  = pa[j];                                                      \
        float b1 = (j >= 1) ? pa[j - 1] : PADV;                                \
        float c2 = (j >= 2) ? pa[j - 2] : PADV;                                \
        float c2e = cnd ? PADV : c2;  /* 2-way lse == 3-way lse with PAD */    \
        float m  = fmaxf(fmaxf(a, b1), c2e);                                   \
        float lse = m + logf(expf(a - m) + expf(b1 - m) + expf(c2e - m));      \
        int delta = (a >= b1 && a >= c2e) ? 0 : ((b1 >= c2e) ? 1 : 2);         \
        pb[j] = rr + lse;                                                      \
        unsigned long long mm0 = __ballot(delta & 1);                          \
        unsigned long long mm1 = __ballot(delta >> 1);                         \
        if ((j & 63) == 0) {                                                   \
            bpm[tcur][j >> 6][0] = mm0;                                        \
            bpm[tcur][j >> 6][1] = mm1;                                        \
        }                                                                      \
        if ((tload) < NT) rr = lb[(size_t)(tload) * NC + col];                 \
        __syncthreads();                                                       \
        float* tpp = pa; pa = pb; pb = tpp;                                    \
    } while (0)

    int t = 1;
    for (; t + 3 < NT; t += 4) {
        STEP(t,     r0, t + 4);
        STEP(t + 1, r1, t + 5);
        STEP(t + 2, r2, t + 6);
        STEP(t + 3, r3, t + 7);
    }
    // tail: t = 509, 510, 511
    STEP(t,     r0, NT);
    STEP(t + 1, r1, NT);
    STEP(t + 2, r2, NT);
#undef STEP

    // pa now holds dp[T-1]
    if (j == 0) {
        int Y = yl[b];
        float d1 = pa[Y - 1];
        float d2 = pa[Y - 2];
        float mm = fmaxf(d1, d2);
        float la = mm + logf(expf(d1 - mm) + expf(d2 - mm));
        loss_out[b] = -la * 2.0f / (float)(Y - 1);

        int w = (d1 > d2) ? (Y - 1) : (Y - 2);
        for (int tt = NT - 1; tt >= 1; --tt) {
            wl[tt] = w;
            int wv = w >> 6, ln = w & 63;
            unsigned long long m0 = bpm[tt][wv][0];
            unsigned long long m1 = bpm[tt][wv][1];
            int dd = (int)((m0 >> ln) & 1ULL) + 2 * (int)((m1 >> ln) & 1ULL);
            w -= dd;
        }
        wl[0] = w;   // bp at t=0 is identity
    }
    __syncthreads();
    for (int tt = j; tt < NT; tt += SCANBLK) wout[b * NT + tt] = wl[tt];
}

// ---------------------------------------------------------------------------
// Kernel 2: one-hot align write, as float32 (covers the whole align output)
// ---------------------------------------------------------------------------
__global__ void ctc_align_kernel(const int* __restrict__ w,   // [B*T]
                                 float* __restrict__ out)     // [B][T][LABT]
{
    int tid = blockIdx.x * blockDim.x + threadIdx.x;
    if (tid >= NB * NT * LABT) return;
    int j  = tid % LABT;
    int bt = tid / LABT;      // == b*NT + t
    out[tid] = (j == w[bt]) ? 1.0f : 0.0f;
}

// ---------------------------------------------------------------------------
extern "C" void kernel_launch(void* const* d_in, const int* in_sizes, int n_in,
                              void* d_out, int out_size, void* d_ws, size_t ws_size,
                              hipStream_t stream)
{
    const float* logit = (const float*)d_in[0];
    const int*   label = (const int*)d_in[1];
    const int*   blank = (const int*)d_in[2];

    float* out = (float*)d_out;   // [B*T*LABT] align (0/1 float) then [B] loss
    int*   ws  = (int*)d_ws;

    int* ext_idx = ws;                        // 32*129 = 4128 ints
    int* cond    = ws + NB * LABT;            // 4128 ints
    int* yl      = ws + 2 * NB * LABT;        // 32 ints
    int* w       = ws + 2 * NB * LABT + NB;   // 32*512 ints

    ctc_prep_kernel<<<NB, SCANBLK, 0, stream>>>(label, blank, ext_idx, cond, yl);
    ctc_scan_kernel<<<NB, SCANBLK, 0, stream>>>(logit, ext_idx, cond, yl, w,
                                                out + NB * NT * LABT);
    int total = NB * NT * LABT;
    ctc_align_kernel<<<(total + 255) / 256, 256, 0, stream>>>(w, out);
}